// Round 10
// baseline (3111.085 us; speedup 1.0000x reference)
//
#include <hip/hip_runtime.h>

// Problem constants
#define Bsz 131072
#define Dd  256
#define Ll  4
#define Kk  1024
#define TB  32                 // vectors per workgroup
#define NWG (Bsz / TB)         // 4096
#define NT  256                // threads per block (4 waves)
#define CAP 1024               // candidate list capacity per WG-level
#define MARGIN 0.05f           // >> 2x worst-case bf16 screening error

// Output layout (element offsets into float32 d_out, concat in return order)
#define O_IDX   0ULL                                   // indices      [B][L]
#define O_QSTK  524288ULL                              // quant_stack  [B][L][D]
#define O_QSUM  (O_QSTK + (size_t)Bsz * Ll * Dd)       // quant_sum    [B][D]
#define O_QSQ   (O_QSUM + (size_t)Bsz * Dd)            // quant_sum_qs [B][D]
#define O_RES   (O_QSQ  + (size_t)Bsz * Dd)            // res_states   [L+1][B][D]
#define O_LOSS  (O_RES  + (size_t)(Ll + 1) * Bsz * Dd) // 3 scalars

// ws layout: [0,16384) per-WG/level ssq partials; [16384,20480) c2 (np-exact);
// float-offset 32768: bf16 codebook copy CBH[l][k][d] (ushort, 2 MB)
#define WS_C2_OFF  16384
#define WS_CBH_OFF 32768

typedef short v8s __attribute__((ext_vector_type(8)));
typedef float v4f __attribute__((ext_vector_type(4)));

__device__ __forceinline__ unsigned short f2bf(float f) {   // RNE f32->bf16
    unsigned u = __float_as_uint(f);
    return (unsigned short)((u + 0x7fffu + ((u >> 16) & 1u)) >> 16);
}

// ---------------------------------------------------------------------------
// numpy-mirror row sum-of-squares, serial form (used by prep kernel)
// ---------------------------------------------------------------------------
__device__ __forceinline__ float np_rowsum_sq(const float* a) {
    float blk[2];
    #pragma unroll
    for (int hb = 0; hb < 2; ++hb) {
        const float* p = a + hb * 128;
        float r8[8][4];
        #pragma unroll
        for (int j = 0; j < 8; ++j) {
            float4 x = *(const float4*)(p + 4 * j);
            r8[j][0] = __fmul_rn(x.x, x.x);
            r8[j][1] = __fmul_rn(x.y, x.y);
            r8[j][2] = __fmul_rn(x.z, x.z);
            r8[j][3] = __fmul_rn(x.w, x.w);
        }
        #pragma unroll
        for (int i = 32; i < 128; i += 32) {
            #pragma unroll
            for (int j = 0; j < 8; ++j) {
                float4 x = *(const float4*)(p + i + 4 * j);
                r8[j][0] = __fadd_rn(r8[j][0], __fmul_rn(x.x, x.x));
                r8[j][1] = __fadd_rn(r8[j][1], __fmul_rn(x.y, x.y));
                r8[j][2] = __fadd_rn(r8[j][2], __fmul_rn(x.z, x.z));
                r8[j][3] = __fadd_rn(r8[j][3], __fmul_rn(x.w, x.w));
            }
        }
        float wv[4];
        #pragma unroll
        for (int L = 0; L < 4; ++L) {
            wv[L] = __fadd_rn(
                __fadd_rn(__fadd_rn(r8[0][L], r8[1][L]), __fadd_rn(r8[2][L], r8[3][L])),
                __fadd_rn(__fadd_rn(r8[4][L], r8[5][L]), __fadd_rn(r8[6][L], r8[7][L])));
        }
        blk[hb] = __fadd_rn(__fadd_rn(wv[0], wv[1]), __fadd_rn(wv[2], wv[3]));
    }
    return __fadd_rn(blk[0], blk[1]);
}

__global__ void prep_kernel(const float* __restrict__ cbks, float* __restrict__ ws) {
    int t = blockIdx.x * 256 + threadIdx.x;
    if (t < Ll * Kk) ws[WS_C2_OFF + t] = np_rowsum_sq(cbks + (size_t)t * Dd);
}

// bf16 copy of codebook, same [l][k][d] layout (k-contig d = MFMA K-dim)
__global__ void cvt_kernel(const float* __restrict__ cbks, float* __restrict__ ws) {
    unsigned short* cbh = (unsigned short*)(ws + WS_CBH_OFF);
    int i = (blockIdx.x * 256 + threadIdx.x) * 4;
    float4 x = *(const float4*)(cbks + i);
    ushort4 y;
    y.x = f2bf(x.x); y.y = f2bf(x.y); y.z = f2bf(x.z); y.w = f2bf(x.w);
    *(ushort4*)(cbh + i) = y;
}

// ---------------------------------------------------------------------------
// main kernel: WG (256 thr, 4 waves) owns 32 vectors through all 4 levels.
// fp32 residual lives in GLOBAL (res_states[l], block-local, L2-hot);
// LDS holds only the bf16 screen copy + candidate list (~21 KB -> 4 blk/CU).
// ---------------------------------------------------------------------------
__global__ __launch_bounds__(NT, 4) void rvq_kernel(
    const float* __restrict__ ze, const float* __restrict__ cbks,
    float* __restrict__ out, float* __restrict__ ws)
{
    __shared__ unsigned short rb16[TB * Dd];     // bf16 residual, XOR-swizzled
    __shared__ float  r2s[TB];
    __shared__ unsigned long long best64[TB];
    __shared__ int    clist[CAP];
    __shared__ int    ccount;
    __shared__ float  wssq[4];

    const int tid  = threadIdx.x;
    const int wg   = blockIdx.x;
    const int b0   = wg * TB;
    const int lane = tid & 63;
    const int w    = tid >> 6;     // wave id 0..3
    const int lrow = lane & 15;    // MFMA row/col lane index
    const int lk   = lane >> 4;    // MFMA k-group

    const float* c2  = ws + WS_C2_OFF;
    const unsigned short* cbh = (const unsigned short*)(ws + WS_CBH_OFF);

    // res_states[0] = ze  (residual source of truth lives in global out)
    for (int i = tid; i < TB * Dd / 4; i += NT) {
        int v  = i >> 6;
        int dp = (i & 63) << 2;
        float4 x = *(const float4*)(ze + (size_t)(b0 + v) * Dd + dp);
        *(float4*)(out + O_RES + (size_t)(b0 + v) * Dd + dp) = x;
    }
    __syncthreads();

    for (int l = 0; l < Ll; ++l) {
        const float* resl = out + O_RES + (size_t)l * Bsz * Dd;       // level-l residual
        float*       resn = out + O_RES + (size_t)(l + 1) * Bsz * Dd; // level-l+1

        // ---- wave-parallel np-exact r2: 16 threads/row, 2 row passes ----
        #pragma unroll
        for (int it = 0; it < 2; ++it) {
            const int row = (tid >> 4) + it * 16;
            const int sub = tid & 15;
            const int j   = sub & 7;
            const int hb  = sub >> 3;
            const float* p = resl + (size_t)(b0 + row) * Dd + hb * 128 + j * 4;
            float4 x = *(const float4*)p;
            float q0 = __fmul_rn(x.x, x.x), q1 = __fmul_rn(x.y, x.y);
            float q2 = __fmul_rn(x.z, x.z), q3 = __fmul_rn(x.w, x.w);
            #pragma unroll
            for (int i = 32; i < 128; i += 32) {
                float4 y = *(const float4*)(p + i);
                q0 = __fadd_rn(q0, __fmul_rn(y.x, y.x));
                q1 = __fadd_rn(q1, __fmul_rn(y.y, y.y));
                q2 = __fadd_rn(q2, __fmul_rn(y.z, y.z));
                q3 = __fadd_rn(q3, __fmul_rn(y.w, y.w));
            }
            #pragma unroll
            for (int m = 1; m < 8; m <<= 1) {
                q0 = __fadd_rn(q0, __shfl_xor(q0, m));
                q1 = __fadd_rn(q1, __shfl_xor(q1, m));
                q2 = __fadd_rn(q2, __shfl_xor(q2, m));
                q3 = __fadd_rn(q3, __shfl_xor(q3, m));
            }
            float blk = __fadd_rn(__fadd_rn(q0, q1), __fadd_rn(q2, q3));
            float tot = __fadd_rn(blk, __shfl_xor(blk, 8));
            if (sub == 0) { r2s[row] = tot; best64[row] = ~0ull; }
        }
        if (tid == 0) ccount = 0;
        // ---- bf16 residual copy (global -> LDS), XOR bank swizzle ----
        for (int gi = tid; gi < TB * 32; gi += NT) {
            int v = gi >> 5, g = gi & 31;
            const float* rp = resl + (size_t)(b0 + v) * Dd + g * 8;
            float4 x0 = *(const float4*)rp;
            float4 x1 = *(const float4*)(rp + 4);
            v8s o;
            o[0] = (short)f2bf(x0.x); o[1] = (short)f2bf(x0.y);
            o[2] = (short)f2bf(x0.z); o[3] = (short)f2bf(x0.w);
            o[4] = (short)f2bf(x1.x); o[5] = (short)f2bf(x1.y);
            o[6] = (short)f2bf(x1.z); o[7] = (short)f2bf(x1.w);
            *(v8s*)&rb16[v * Dd + ((g ^ (v & 7)) << 3)] = o;
        }
        __syncthreads();

        const unsigned short* cbh_l = cbh + (size_t)l * Kk * Dd;
        const float* c2l = c2 + l * Kk;
        const float* cb  = cbks + (size_t)l * Kk * Dd;

        // ---- MFMA screening: wave w covers codes [w*256, w*256+256) ----
        const unsigned short* ap0 = &rb16[(size_t)lrow * Dd];
        const unsigned short* ap1 = &rb16[(size_t)(lrow + 16) * Dd];
        const int axor = lrow & 7;
        float mr[2][4];                // per-lane running row-min (registers)
        #pragma unroll
        for (int rt = 0; rt < 2; ++rt)
            #pragma unroll
            for (int reg = 0; reg < 4; ++reg) mr[rt][reg] = 1e30f;

        #pragma unroll
        for (int sc = 0; sc < 4; ++sc) {
            const int cbase = w * 256 + sc * 64;
            v4f acc[2][4];
            #pragma unroll
            for (int rt = 0; rt < 2; ++rt)
                #pragma unroll
                for (int ct = 0; ct < 4; ++ct) acc[rt][ct] = (v4f)(0.f);

            const unsigned short* bp[4];
            #pragma unroll
            for (int ct = 0; ct < 4; ++ct)
                bp[ct] = cbh_l + (size_t)(cbase + ct * 16 + lrow) * Dd + lk * 8;

            #pragma unroll
            for (int ks = 0; ks < 8; ++ks) {
                int aoff = (((ks * 4 + lk) ^ axor) << 3);
                v8s a0 = *(const v8s*)(ap0 + aoff);
                v8s a1 = *(const v8s*)(ap1 + aoff);
                #pragma unroll
                for (int ct = 0; ct < 4; ++ct) {
                    v8s b = *(const v8s*)(bp[ct] + ks * 32);
                    acc[0][ct] = __builtin_amdgcn_mfma_f32_16x16x32_bf16(a0, b, acc[0][ct], 0, 0, 0);
                    acc[1][ct] = __builtin_amdgcn_mfma_f32_16x16x32_bf16(a1, b, acc[1][ct], 0, 0, 0);
                }
            }

            float c2v[4];
            #pragma unroll
            for (int ct = 0; ct < 4; ++ct) c2v[ct] = c2l[cbase + ct * 16 + lrow];

            // candidate collection: C-layout col=lane&15, row=(lane>>4)*4+reg
            #pragma unroll
            for (int rt = 0; rt < 2; ++rt) {
                #pragma unroll
                for (int reg = 0; reg < 4; ++reg) {
                    int row = rt * 16 + lk * 4 + reg;
                    float t0 = c2v[0] - 2.f * acc[rt][0][reg];
                    float t1 = c2v[1] - 2.f * acc[rt][1][reg];
                    float t2 = c2v[2] - 2.f * acc[rt][2][reg];
                    float t3 = c2v[3] - 2.f * acc[rt][3][reg];
                    float pm = fminf(fminf(t0, t1), fminf(t2, t3));
                    pm = fminf(pm, __shfl_xor(pm, 1));
                    pm = fminf(pm, __shfl_xor(pm, 2));
                    pm = fminf(pm, __shfl_xor(pm, 4));
                    pm = fminf(pm, __shfl_xor(pm, 8));
                    float nm = fminf(mr[rt][reg], pm);
                    mr[rt][reg] = nm;
                    float th = nm + MARGIN;
                    if (t0 < th) { int p = atomicAdd(&ccount, 1); if (p < CAP) clist[p] = (row << 10) | (cbase + 0 * 16 + lrow); }
                    if (t1 < th) { int p = atomicAdd(&ccount, 1); if (p < CAP) clist[p] = (row << 10) | (cbase + 1 * 16 + lrow); }
                    if (t2 < th) { int p = atomicAdd(&ccount, 1); if (p < CAP) clist[p] = (row << 10) | (cbase + 2 * 16 + lrow); }
                    if (t3 < th) { int p = atomicAdd(&ccount, 1); if (p < CAP) clist[p] = (row << 10) | (cbase + 3 * 16 + lrow); }
                }
            }
        }
        __syncthreads();

        // ---- exact np-order rescore of candidates (residual from global) ----
        {
            int cnt = ccount;
            int total = (cnt <= CAP) ? cnt : (TB * Kk);
            for (int ci = tid; ci < total; ci += NT) {
                int row, code;
                if (cnt <= CAP) { int rc = clist[ci]; row = rc >> 10; code = rc & 1023; }
                else            { row = ci >> 10; code = ci & 1023; }
                const float* cp = cb + (size_t)code * Dd;
                const float* rp = resl + (size_t)(b0 + row) * Dd;
                float a = 0.f;
                #pragma unroll 4
                for (int d = 0; d < Dd; d += 4) {
                    float4 cv = *(const float4*)(cp + d);
                    float4 rv = *(const float4*)(rp + d);
                    a = __fmaf_rn(rv.x, cv.x, a);
                    a = __fmaf_rn(rv.y, cv.y, a);
                    a = __fmaf_rn(rv.z, cv.z, a);
                    a = __fmaf_rn(rv.w, cv.w, a);
                }
                float s = __fsub_rn(__fadd_rn(r2s[row], c2l[code]), 2.0f * a);
                unsigned long long pk =
                    (((unsigned long long)__float_as_uint(s)) << 32) | (unsigned)code;
                atomicMin(&best64[row], pk);
            }
        }
        __syncthreads();

        // ---- gather chosen codes, update residual, emit outputs (exact) ----
        float ssq = 0.f;
        for (int v = w * 8; v < w * 8 + 8; ++v) {
            int idx = (int)(best64[v] & 0xffffffffu);
            if (lane == 0) out[O_IDX + (size_t)(b0 + v) * Ll + l] = (float)idx;
            size_t gb = (size_t)(b0 + v);
            const float4 q = *(const float4*)(cb + (size_t)idx * Dd + (lane << 2));
            const float4 r = *(const float4*)(resl + gb * Dd + (lane << 2));
            float4 nr = make_float4(r.x - q.x, r.y - q.y, r.z - q.z, r.w - q.w);
            *(float4*)(out + O_QSTK + ((gb * Ll) + l) * Dd + (lane << 2)) = q;
            *(float4*)(resn + gb * Dd + (lane << 2)) = nr;
            ssq += nr.x * nr.x + nr.y * nr.y + nr.z * nr.z + nr.w * nr.w;
        }
        #pragma unroll
        for (int m = 32; m; m >>= 1) ssq += __shfl_xor(ssq, m);
        if (lane == 0) wssq[w] = ssq;
        __syncthreads();
        if (tid == 0)
            ws[wg * 4 + l] = wssq[0] + wssq[1] + wssq[2] + wssq[3];
        __syncthreads();   // resn writes drained before next level reads them
    }

    // ---- quantized_sum = ze - final_residual; qspace = ze + (qsum - ze) ----
    const float* res4 = out + O_RES + (size_t)Ll * Bsz * Dd;
    for (int i = tid; i < TB * Dd / 4; i += NT) {
        int v  = i >> 6;
        int dp = (i & 63) << 2;
        size_t gb = (size_t)(b0 + v);
        float4 z = *(const float4*)(ze + gb * Dd + dp);
        float4 r = *(const float4*)(res4 + gb * Dd + dp);
        float4 qs = make_float4(z.x - r.x, z.y - r.y, z.z - r.z, z.w - r.w);
        *(float4*)(out + O_QSUM + gb * Dd + dp) = qs;
        float4 qq = make_float4(z.x + (qs.x - z.x), z.y + (qs.y - z.y),
                                z.z + (qs.z - z.z), z.w + (qs.w - z.w));
        *(float4*)(out + O_QSQ + gb * Dd + dp) = qq;
    }
}

// ---------------------------------------------------------------------------
// loss: deterministic reduction of per-WG partials -> 3 scalars
// ---------------------------------------------------------------------------
__global__ void loss_kernel(const float* __restrict__ ws, float* __restrict__ out) {
    __shared__ float red[Ll * 4];
    int tid = threadIdx.x;
    int lane = tid & 63, w = tid >> 6;
    for (int l = 0; l < Ll; ++l) {
        float s = 0.f;
        for (int i = tid; i < NWG; i += 256) s += ws[i * 4 + l];
        #pragma unroll
        for (int m = 32; m; m >>= 1) s += __shfl_xor(s, m);
        if (lane == 0) red[l * 4 + w] = s;
    }
    __syncthreads();
    if (tid == 0) {
        float tot = 0.f;
        for (int l = 0; l < Ll; ++l)
            tot += red[l * 4 + 0] + red[l * 4 + 1] + red[l * 4 + 2] + red[l * 4 + 3];
        float cm = tot / (float)((size_t)Ll * Bsz * Dd);
        out[O_LOSS + 0] = cm;                    // commitment_loss
        out[O_LOSS + 1] = cm;                    // codebook_loss
        out[O_LOSS + 2] = 0.25f * cm + cm;       // quantization_loss
    }
}

extern "C" void kernel_launch(void* const* d_in, const int* in_sizes, int n_in,
                              void* d_out, int out_size, void* d_ws, size_t ws_size,
                              hipStream_t stream) {
    (void)in_sizes; (void)n_in; (void)out_size; (void)ws_size;
    const float* ze   = (const float*)d_in[0];
    const float* cbks = (const float*)d_in[1];
    float* out = (float*)d_out;
    float* ws  = (float*)d_ws;

    hipLaunchKernelGGL(prep_kernel, dim3(16), dim3(256), 0, stream, cbks, ws);
    hipLaunchKernelGGL(cvt_kernel, dim3(Ll * Kk * Dd / 1024), dim3(256), 0, stream, cbks, ws);
    hipLaunchKernelGGL(rvq_kernel, dim3(NWG), dim3(NT), 0, stream, ze, cbks, out, ws);
    hipLaunchKernelGGL(loss_kernel, dim3(1), dim3(256), 0, stream, ws, out);
}

// Round 11
// 2589.868 us; speedup vs baseline: 1.2013x; 1.2013x over previous
//
#include <hip/hip_runtime.h>

// Problem constants
#define Bsz 131072
#define Dd  256
#define Ll  4
#define Kk  1024
#define TB  32                 // vectors per workgroup
#define NWG (Bsz / TB)         // 4096
#define NT  256                // threads per block (4 waves)
#define CAP 768                // candidate list capacity per WG-level
#define MARGIN 0.05f           // >> 2x worst-case bf16 screening error

// Output layout (element offsets into float32 d_out, concat in return order)
#define O_IDX   0ULL                                   // indices      [B][L]
#define O_QSTK  524288ULL                              // quant_stack  [B][L][D]
#define O_QSUM  (O_QSTK + (size_t)Bsz * Ll * Dd)       // quant_sum    [B][D]
#define O_QSQ   (O_QSUM + (size_t)Bsz * Dd)            // quant_sum_qs [B][D]
#define O_RES   (O_QSQ  + (size_t)Bsz * Dd)            // res_states   [L+1][B][D]
#define O_LOSS  (O_RES  + (size_t)(Ll + 1) * Bsz * Dd) // 3 scalars

// ws layout: [0,16384) per-WG/level ssq partials; [16384,20480) c2 (np-exact);
// float-offset 32768: bf16 codebook copy CBH[l][k][d] (ushort, 2 MB)
#define WS_C2_OFF  16384
#define WS_CBH_OFF 32768

typedef short v8s __attribute__((ext_vector_type(8)));
typedef float v4f __attribute__((ext_vector_type(4)));

__device__ __forceinline__ unsigned short f2bf(float f) {   // RNE f32->bf16
    unsigned u = __float_as_uint(f);
    return (unsigned short)((u + 0x7fffu + ((u >> 16) & 1u)) >> 16);
}

// swizzled float-granule index into rbuf: row 0..31, g = d>>2 (0..63)
__device__ __forceinline__ int ridx(int row, int g) {
    return (row << 8) + ((g ^ (row & 7)) << 2);
}

// ---------------------------------------------------------------------------
// numpy-mirror row sum-of-squares, serial form (used by prep kernel)
// ---------------------------------------------------------------------------
__device__ __forceinline__ float np_rowsum_sq(const float* a) {
    float blk[2];
    #pragma unroll
    for (int hb = 0; hb < 2; ++hb) {
        const float* p = a + hb * 128;
        float r8[8][4];
        #pragma unroll
        for (int j = 0; j < 8; ++j) {
            float4 x = *(const float4*)(p + 4 * j);
            r8[j][0] = __fmul_rn(x.x, x.x);
            r8[j][1] = __fmul_rn(x.y, x.y);
            r8[j][2] = __fmul_rn(x.z, x.z);
            r8[j][3] = __fmul_rn(x.w, x.w);
        }
        #pragma unroll
        for (int i = 32; i < 128; i += 32) {
            #pragma unroll
            for (int j = 0; j < 8; ++j) {
                float4 x = *(const float4*)(p + i + 4 * j);
                r8[j][0] = __fadd_rn(r8[j][0], __fmul_rn(x.x, x.x));
                r8[j][1] = __fadd_rn(r8[j][1], __fmul_rn(x.y, x.y));
                r8[j][2] = __fadd_rn(r8[j][2], __fmul_rn(x.z, x.z));
                r8[j][3] = __fadd_rn(r8[j][3], __fmul_rn(x.w, x.w));
            }
        }
        float wv[4];
        #pragma unroll
        for (int L = 0; L < 4; ++L) {
            wv[L] = __fadd_rn(
                __fadd_rn(__fadd_rn(r8[0][L], r8[1][L]), __fadd_rn(r8[2][L], r8[3][L])),
                __fadd_rn(__fadd_rn(r8[4][L], r8[5][L]), __fadd_rn(r8[6][L], r8[7][L])));
        }
        blk[hb] = __fadd_rn(__fadd_rn(wv[0], wv[1]), __fadd_rn(wv[2], wv[3]));
    }
    return __fadd_rn(blk[0], blk[1]);
}

__global__ void prep_kernel(const float* __restrict__ cbks, float* __restrict__ ws) {
    int t = blockIdx.x * 256 + threadIdx.x;
    if (t < Ll * Kk) ws[WS_C2_OFF + t] = np_rowsum_sq(cbks + (size_t)t * Dd);
}

// bf16 copy of codebook, same [l][k][d] layout (k-contig d = MFMA K-dim)
__global__ void cvt_kernel(const float* __restrict__ cbks, float* __restrict__ ws) {
    unsigned short* cbh = (unsigned short*)(ws + WS_CBH_OFF);
    int i = (blockIdx.x * 256 + threadIdx.x) * 4;
    float4 x = *(const float4*)(cbks + i);
    ushort4 y;
    y.x = f2bf(x.x); y.y = f2bf(x.y); y.z = f2bf(x.z); y.w = f2bf(x.w);
    *(ushort4*)(cbh + i) = y;
}

// ---------------------------------------------------------------------------
// main kernel: WG (256 thr, 4 waves) owns 32 vectors through all 4 levels.
// fp32 residual in LDS (XOR-swizzled granules, no pad); bf16 copy for MFMA
// screen; candidate list + exact np rescore; epilogue fused into last level.
// LDS ~51.4 KB -> 3 blocks/CU (12 waves/CU).
// ---------------------------------------------------------------------------
__global__ __launch_bounds__(NT, 3) void rvq_kernel(
    const float* __restrict__ ze, const float* __restrict__ cbks,
    float* __restrict__ out, float* __restrict__ ws)
{
    __shared__ float  rbuf[TB * Dd];             // fp32 residual, swizzled granules
    __shared__ unsigned short rb16[TB * Dd];     // bf16 residual, XOR-swizzled
    __shared__ float  r2s[TB];
    __shared__ unsigned long long best64[TB];
    __shared__ int    clist[CAP];
    __shared__ int    ccount;
    __shared__ float  wssq[4];

    const int tid  = threadIdx.x;
    const int wg   = blockIdx.x;
    const int b0   = wg * TB;
    const int lane = tid & 63;
    const int w    = tid >> 6;     // wave id 0..3
    const int lrow = lane & 15;    // MFMA row/col lane index
    const int lk   = lane >> 4;    // MFMA k-group

    const float* c2  = ws + WS_C2_OFF;
    const unsigned short* cbh = (const unsigned short*)(ws + WS_CBH_OFF);

    // Load ze tile -> rbuf (swizzled), write residual_states[0] = ze
    for (int i = tid; i < TB * Dd / 4; i += NT) {
        int v  = i >> 6;
        int g  = i & 63;
        float4 x = *(const float4*)(ze + (size_t)(b0 + v) * Dd + (g << 2));
        *(float4*)&rbuf[ridx(v, g)] = x;
        *(float4*)(out + O_RES + (size_t)(b0 + v) * Dd + (g << 2)) = x;
    }
    __syncthreads();

    for (int l = 0; l < Ll; ++l) {
        // ---- wave-parallel np-exact r2: 16 threads/row, 2 row passes ----
        #pragma unroll
        for (int it = 0; it < 2; ++it) {
            const int row = (tid >> 4) + it * 16;
            const int sub = tid & 15;
            const int j   = sub & 7;
            const int hb  = sub >> 3;
            const int g0  = hb * 32 + j;
            float4 x = *(const float4*)&rbuf[ridx(row, g0)];
            float q0 = __fmul_rn(x.x, x.x), q1 = __fmul_rn(x.y, x.y);
            float q2 = __fmul_rn(x.z, x.z), q3 = __fmul_rn(x.w, x.w);
            #pragma unroll
            for (int i = 1; i < 4; ++i) {
                float4 y = *(const float4*)&rbuf[ridx(row, g0 + i * 8)];
                q0 = __fadd_rn(q0, __fmul_rn(y.x, y.x));
                q1 = __fadd_rn(q1, __fmul_rn(y.y, y.y));
                q2 = __fadd_rn(q2, __fmul_rn(y.z, y.z));
                q3 = __fadd_rn(q3, __fmul_rn(y.w, y.w));
            }
            #pragma unroll
            for (int m = 1; m < 8; m <<= 1) {
                q0 = __fadd_rn(q0, __shfl_xor(q0, m));
                q1 = __fadd_rn(q1, __shfl_xor(q1, m));
                q2 = __fadd_rn(q2, __shfl_xor(q2, m));
                q3 = __fadd_rn(q3, __shfl_xor(q3, m));
            }
            float blk = __fadd_rn(__fadd_rn(q0, q1), __fadd_rn(q2, q3));
            float tot = __fadd_rn(blk, __shfl_xor(blk, 8));
            if (sub == 0) { r2s[row] = tot; best64[row] = ~0ull; }
        }
        if (tid == 0) ccount = 0;
        // ---- bf16 residual copy (LDS fp32 -> LDS bf16), XOR bank swizzle ----
        for (int gi = tid; gi < TB * 32; gi += NT) {
            int v = gi >> 5, g = gi & 31;
            float4 x0 = *(const float4*)&rbuf[ridx(v, 2 * g)];
            float4 x1 = *(const float4*)&rbuf[ridx(v, 2 * g + 1)];
            v8s o;
            o[0] = (short)f2bf(x0.x); o[1] = (short)f2bf(x0.y);
            o[2] = (short)f2bf(x0.z); o[3] = (short)f2bf(x0.w);
            o[4] = (short)f2bf(x1.x); o[5] = (short)f2bf(x1.y);
            o[6] = (short)f2bf(x1.z); o[7] = (short)f2bf(x1.w);
            *(v8s*)&rb16[v * Dd + ((g ^ (v & 7)) << 3)] = o;
        }
        __syncthreads();

        const unsigned short* cbh_l = cbh + (size_t)l * Kk * Dd;
        const float* c2l = c2 + l * Kk;
        const float* cb  = cbks + (size_t)l * Kk * Dd;

        // ---- MFMA screening: wave w covers codes [w*256, w*256+256) ----
        const unsigned short* ap0 = &rb16[(size_t)lrow * Dd];
        const unsigned short* ap1 = &rb16[(size_t)(lrow + 16) * Dd];
        const int axor = lrow & 7;
        float mr[2][4];                // per-lane running row-min (registers)
        #pragma unroll
        for (int rt = 0; rt < 2; ++rt)
            #pragma unroll
            for (int reg = 0; reg < 4; ++reg) mr[rt][reg] = 1e30f;

        #pragma unroll
        for (int sc = 0; sc < 4; ++sc) {
            const int cbase = w * 256 + sc * 64;
            v4f acc[2][4];
            #pragma unroll
            for (int rt = 0; rt < 2; ++rt)
                #pragma unroll
                for (int ct = 0; ct < 4; ++ct) acc[rt][ct] = (v4f)(0.f);

            const unsigned short* bp[4];
            #pragma unroll
            for (int ct = 0; ct < 4; ++ct)
                bp[ct] = cbh_l + (size_t)(cbase + ct * 16 + lrow) * Dd + lk * 8;

            #pragma unroll
            for (int ks = 0; ks < 8; ++ks) {
                int aoff = (((ks * 4 + lk) ^ axor) << 3);
                v8s a0 = *(const v8s*)(ap0 + aoff);
                v8s a1 = *(const v8s*)(ap1 + aoff);
                #pragma unroll
                for (int ct = 0; ct < 4; ++ct) {
                    v8s b = *(const v8s*)(bp[ct] + ks * 32);
                    acc[0][ct] = __builtin_amdgcn_mfma_f32_16x16x32_bf16(a0, b, acc[0][ct], 0, 0, 0);
                    acc[1][ct] = __builtin_amdgcn_mfma_f32_16x16x32_bf16(a1, b, acc[1][ct], 0, 0, 0);
                }
            }

            float c2v[4];
            #pragma unroll
            for (int ct = 0; ct < 4; ++ct) c2v[ct] = c2l[cbase + ct * 16 + lrow];

            // candidate collection: C-layout col=lane&15, row=(lane>>4)*4+reg
            #pragma unroll
            for (int rt = 0; rt < 2; ++rt) {
                #pragma unroll
                for (int reg = 0; reg < 4; ++reg) {
                    int row = rt * 16 + lk * 4 + reg;
                    float t0 = c2v[0] - 2.f * acc[rt][0][reg];
                    float t1 = c2v[1] - 2.f * acc[rt][1][reg];
                    float t2 = c2v[2] - 2.f * acc[rt][2][reg];
                    float t3 = c2v[3] - 2.f * acc[rt][3][reg];
                    float pm = fminf(fminf(t0, t1), fminf(t2, t3));
                    pm = fminf(pm, __shfl_xor(pm, 1));
                    pm = fminf(pm, __shfl_xor(pm, 2));
                    pm = fminf(pm, __shfl_xor(pm, 4));
                    pm = fminf(pm, __shfl_xor(pm, 8));
                    float nm = fminf(mr[rt][reg], pm);
                    mr[rt][reg] = nm;
                    float th = nm + MARGIN;
                    if (t0 < th) { int p = atomicAdd(&ccount, 1); if (p < CAP) clist[p] = (row << 10) | (cbase + 0 * 16 + lrow); }
                    if (t1 < th) { int p = atomicAdd(&ccount, 1); if (p < CAP) clist[p] = (row << 10) | (cbase + 1 * 16 + lrow); }
                    if (t2 < th) { int p = atomicAdd(&ccount, 1); if (p < CAP) clist[p] = (row << 10) | (cbase + 2 * 16 + lrow); }
                    if (t3 < th) { int p = atomicAdd(&ccount, 1); if (p < CAP) clist[p] = (row << 10) | (cbase + 3 * 16 + lrow); }
                }
            }
        }
        __syncthreads();

        // ---- exact np-order rescore of candidates (fallback: all pairs) ----
        {
            int cnt = ccount;
            int total = (cnt <= CAP) ? cnt : (TB * Kk);
            for (int ci = tid; ci < total; ci += NT) {
                int row, code;
                if (cnt <= CAP) { int rc = clist[ci]; row = rc >> 10; code = rc & 1023; }
                else            { row = ci >> 10; code = ci & 1023; }
                const float* cp = cb + (size_t)code * Dd;
                float a = 0.f;
                #pragma unroll 4
                for (int g = 0; g < 64; ++g) {
                    float4 cv = *(const float4*)(cp + (g << 2));
                    float4 rv = *(const float4*)&rbuf[ridx(row, g)];
                    a = __fmaf_rn(rv.x, cv.x, a);
                    a = __fmaf_rn(rv.y, cv.y, a);
                    a = __fmaf_rn(rv.z, cv.z, a);
                    a = __fmaf_rn(rv.w, cv.w, a);
                }
                float s = __fsub_rn(__fadd_rn(r2s[row], c2l[code]), 2.0f * a);
                unsigned long long pk =
                    (((unsigned long long)__float_as_uint(s)) << 32) | (unsigned)code;
                atomicMin(&best64[row], pk);
            }
        }
        __syncthreads();

        // ---- gather chosen codes, update residual, emit outputs (exact);
        //      final level also emits quantized_sum / qspace (fused epilogue)
        float ssq = 0.f;
        for (int v = w * 8; v < w * 8 + 8; ++v) {
            int idx = (int)(best64[v] & 0xffffffffu);
            if (lane == 0) out[O_IDX + (size_t)(b0 + v) * Ll + l] = (float)idx;
            size_t gb = (size_t)(b0 + v);
            const float4 q = *(const float4*)(cb + (size_t)idx * Dd + (lane << 2));
            float* rptr = &rbuf[ridx(v, lane)];
            float4 r = *(const float4*)rptr;
            float4 nr = make_float4(r.x - q.x, r.y - q.y, r.z - q.z, r.w - q.w);
            *(float4*)rptr = nr;
            *(float4*)(out + O_QSTK + ((gb * Ll) + l) * Dd + (lane << 2)) = q;
            *(float4*)(out + O_RES + ((size_t)(l + 1) * Bsz + gb) * Dd + (lane << 2)) = nr;
            ssq += nr.x * nr.x + nr.y * nr.y + nr.z * nr.z + nr.w * nr.w;
            if (l == Ll - 1) {
                float4 z = *(const float4*)(ze + gb * Dd + (lane << 2));
                float4 qs = make_float4(z.x - nr.x, z.y - nr.y, z.z - nr.z, z.w - nr.w);
                *(float4*)(out + O_QSUM + gb * Dd + (lane << 2)) = qs;
                float4 qq = make_float4(z.x + (qs.x - z.x), z.y + (qs.y - z.y),
                                        z.z + (qs.z - z.z), z.w + (qs.w - z.w));
                *(float4*)(out + O_QSQ + gb * Dd + (lane << 2)) = qq;
            }
        }
        #pragma unroll
        for (int m = 32; m; m >>= 1) ssq += __shfl_xor(ssq, m);
        if (lane == 0) wssq[w] = ssq;
        __syncthreads();
        if (tid == 0)
            ws[wg * 4 + l] = wssq[0] + wssq[1] + wssq[2] + wssq[3];
        __syncthreads();
    }
}

// ---------------------------------------------------------------------------
// loss: deterministic reduction of per-WG partials -> 3 scalars
// ---------------------------------------------------------------------------
__global__ void loss_kernel(const float* __restrict__ ws, float* __restrict__ out) {
    __shared__ float red[Ll * 4];
    int tid = threadIdx.x;
    int lane = tid & 63, w = tid >> 6;
    for (int l = 0; l < Ll; ++l) {
        float s = 0.f;
        for (int i = tid; i < NWG; i += 256) s += ws[i * 4 + l];
        #pragma unroll
        for (int m = 32; m; m >>= 1) s += __shfl_xor(s, m);
        if (lane == 0) red[l * 4 + w] = s;
    }
    __syncthreads();
    if (tid == 0) {
        float tot = 0.f;
        for (int l = 0; l < Ll; ++l)
            tot += red[l * 4 + 0] + red[l * 4 + 1] + red[l * 4 + 2] + red[l * 4 + 3];
        float cm = tot / (float)((size_t)Ll * Bsz * Dd);
        out[O_LOSS + 0] = cm;                    // commitment_loss
        out[O_LOSS + 1] = cm;                    // codebook_loss
        out[O_LOSS + 2] = 0.25f * cm + cm;       // quantization_loss
    }
}

extern "C" void kernel_launch(void* const* d_in, const int* in_sizes, int n_in,
                              void* d_out, int out_size, void* d_ws, size_t ws_size,
                              hipStream_t stream) {
    (void)in_sizes; (void)n_in; (void)out_size; (void)ws_size;
    const float* ze   = (const float*)d_in[0];
    const float* cbks = (const float*)d_in[1];
    float* out = (float*)d_out;
    float* ws  = (float*)d_ws;

    hipLaunchKernelGGL(prep_kernel, dim3(16), dim3(256), 0, stream, cbks, ws);
    hipLaunchKernelGGL(cvt_kernel, dim3(Ll * Kk * Dd / 1024), dim3(256), 0, stream, cbks, ws);
    hipLaunchKernelGGL(rvq_kernel, dim3(NWG), dim3(NT), 0, stream, ze, cbks, out, ws);
    hipLaunchKernelGGL(loss_kernel, dim3(1), dim3(256), 0, stream, ws, out);
}

// Round 12
// 2396.290 us; speedup vs baseline: 1.2983x; 1.0808x over previous
//
#include <hip/hip_runtime.h>

// Problem constants
#define Bsz 131072
#define Dd  256
#define Ll  4
#define Kk  1024
#define TB  32                 // vectors per workgroup
#define NWG (Bsz / TB)         // 4096
#define NT  256                // threads per block (4 waves)
#define CAPW 192               // candidate capacity per wave per level
#define MARGIN 0.05f           // >> 2x worst-case bf16 screening error

// Output layout (element offsets into float32 d_out, concat in return order)
#define O_IDX   0ULL                                   // indices      [B][L]
#define O_QSTK  524288ULL                              // quant_stack  [B][L][D]
#define O_QSUM  (O_QSTK + (size_t)Bsz * Ll * Dd)       // quant_sum    [B][D]
#define O_QSQ   (O_QSUM + (size_t)Bsz * Dd)            // quant_sum_qs [B][D]
#define O_RES   (O_QSQ  + (size_t)Bsz * Dd)            // res_states   [L+1][B][D]
#define O_LOSS  (O_RES  + (size_t)(Ll + 1) * Bsz * Dd) // 3 scalars

// ws layout: [0,16384) per-WG/level ssq partials; [16384,20480) c2 (np-exact);
// float-offset 32768: bf16 codebook copy CBH[l][k][d] (ushort, 2 MB)
#define WS_C2_OFF  16384
#define WS_CBH_OFF 32768

typedef short v8s __attribute__((ext_vector_type(8)));
typedef float v4f __attribute__((ext_vector_type(4)));

__device__ __forceinline__ unsigned short f2bf(float f) {   // RNE f32->bf16
    unsigned u = __float_as_uint(f);
    return (unsigned short)((u + 0x7fffu + ((u >> 16) & 1u)) >> 16);
}

// ---------------------------------------------------------------------------
// numpy-mirror row sum-of-squares, serial form (used by prep kernel)
// ---------------------------------------------------------------------------
__device__ __forceinline__ float np_rowsum_sq(const float* a) {
    float blk[2];
    #pragma unroll
    for (int hb = 0; hb < 2; ++hb) {
        const float* p = a + hb * 128;
        float r8[8][4];
        #pragma unroll
        for (int j = 0; j < 8; ++j) {
            float4 x = *(const float4*)(p + 4 * j);
            r8[j][0] = __fmul_rn(x.x, x.x);
            r8[j][1] = __fmul_rn(x.y, x.y);
            r8[j][2] = __fmul_rn(x.z, x.z);
            r8[j][3] = __fmul_rn(x.w, x.w);
        }
        #pragma unroll
        for (int i = 32; i < 128; i += 32) {
            #pragma unroll
            for (int j = 0; j < 8; ++j) {
                float4 x = *(const float4*)(p + i + 4 * j);
                r8[j][0] = __fadd_rn(r8[j][0], __fmul_rn(x.x, x.x));
                r8[j][1] = __fadd_rn(r8[j][1], __fmul_rn(x.y, x.y));
                r8[j][2] = __fadd_rn(r8[j][2], __fmul_rn(x.z, x.z));
                r8[j][3] = __fadd_rn(r8[j][3], __fmul_rn(x.w, x.w));
            }
        }
        float wv[4];
        #pragma unroll
        for (int L = 0; L < 4; ++L) {
            wv[L] = __fadd_rn(
                __fadd_rn(__fadd_rn(r8[0][L], r8[1][L]), __fadd_rn(r8[2][L], r8[3][L])),
                __fadd_rn(__fadd_rn(r8[4][L], r8[5][L]), __fadd_rn(r8[6][L], r8[7][L])));
        }
        blk[hb] = __fadd_rn(__fadd_rn(wv[0], wv[1]), __fadd_rn(wv[2], wv[3]));
    }
    return __fadd_rn(blk[0], blk[1]);
}

__global__ void prep_kernel(const float* __restrict__ cbks, float* __restrict__ ws) {
    int t = blockIdx.x * 256 + threadIdx.x;
    if (t < Ll * Kk) ws[WS_C2_OFF + t] = np_rowsum_sq(cbks + (size_t)t * Dd);
}

// bf16 copy of codebook, same [l][k][d] layout (k-contig d = MFMA K-dim)
__global__ void cvt_kernel(const float* __restrict__ cbks, float* __restrict__ ws) {
    unsigned short* cbh = (unsigned short*)(ws + WS_CBH_OFF);
    int i = (blockIdx.x * 256 + threadIdx.x) * 4;
    float4 x = *(const float4*)(cbks + i);
    ushort4 y;
    y.x = f2bf(x.x); y.y = f2bf(x.y); y.z = f2bf(x.z); y.w = f2bf(x.w);
    *(ushort4*)(cbh + i) = y;
}

// ---------------------------------------------------------------------------
// main kernel: WG (256 thr, 4 waves) owns 32 vectors through all 4 levels.
// fp32 residual in LDS (+4 pad); bf16 screen copy (XOR-swizzled); per-wave
// candidate slices (no screen->rescore barrier); streaming epilogue.
// LDS ~53 KB -> 3 blocks/CU.
// ---------------------------------------------------------------------------
__global__ __launch_bounds__(NT, 3) void rvq_kernel(
    const float* __restrict__ ze, const float* __restrict__ cbks,
    float* __restrict__ out, float* __restrict__ ws)
{
    __shared__ float  rbuf[TB][Dd + 4];          // fp32 residual, +4 pad
    __shared__ unsigned short rb16[TB * Dd];     // bf16 residual, XOR-swizzled
    __shared__ float  r2s[TB];
    __shared__ unsigned long long best64[TB];
    __shared__ int    clist[4 * CAPW];           // per-wave slices
    __shared__ int    cc[4];                     // per-wave candidate counts
    __shared__ float  wssq[4];

    const int tid  = threadIdx.x;
    const int wg   = blockIdx.x;
    const int b0   = wg * TB;
    const int lane = tid & 63;
    const int w    = tid >> 6;     // wave id 0..3
    const int lrow = lane & 15;    // MFMA row/col lane index
    const int lk   = lane >> 4;    // MFMA k-group

    const float* c2  = ws + WS_C2_OFF;
    const unsigned short* cbh = (const unsigned short*)(ws + WS_CBH_OFF);

    // Load ze tile -> rbuf, write residual_states[0] = ze
    for (int i = tid; i < TB * Dd / 4; i += NT) {
        int v  = i >> 6;
        int dp = (i & 63) << 2;
        float4 x = *(const float4*)(ze + (size_t)(b0 + v) * Dd + dp);
        *(float4*)&rbuf[v][dp] = x;
        *(float4*)(out + O_RES + (size_t)(b0 + v) * Dd + dp) = x;
    }
    __syncthreads();

    for (int l = 0; l < Ll; ++l) {
        // ---- phase 1: np-exact r2 (16 thr/row), best64 init, cc reset,
        //      bf16 residual copy ----
        #pragma unroll
        for (int it = 0; it < 2; ++it) {
            const int row = (tid >> 4) + it * 16;
            const int sub = tid & 15;
            const int j   = sub & 7;
            const int hb  = sub >> 3;
            const float* p = &rbuf[row][hb * 128 + j * 4];
            float4 x = *(const float4*)p;
            float q0 = __fmul_rn(x.x, x.x), q1 = __fmul_rn(x.y, x.y);
            float q2 = __fmul_rn(x.z, x.z), q3 = __fmul_rn(x.w, x.w);
            #pragma unroll
            for (int i = 32; i < 128; i += 32) {
                float4 y = *(const float4*)(p + i);
                q0 = __fadd_rn(q0, __fmul_rn(y.x, y.x));
                q1 = __fadd_rn(q1, __fmul_rn(y.y, y.y));
                q2 = __fadd_rn(q2, __fmul_rn(y.z, y.z));
                q3 = __fadd_rn(q3, __fmul_rn(y.w, y.w));
            }
            #pragma unroll
            for (int m = 1; m < 8; m <<= 1) {
                q0 = __fadd_rn(q0, __shfl_xor(q0, m));
                q1 = __fadd_rn(q1, __shfl_xor(q1, m));
                q2 = __fadd_rn(q2, __shfl_xor(q2, m));
                q3 = __fadd_rn(q3, __shfl_xor(q3, m));
            }
            float blk = __fadd_rn(__fadd_rn(q0, q1), __fadd_rn(q2, q3));
            float tot = __fadd_rn(blk, __shfl_xor(blk, 8));
            if (sub == 0) { r2s[row] = tot; best64[row] = ~0ull; }
        }
        if (lane == 0) cc[w] = 0;      // own-wave reset (program order suffices)
        for (int gi = tid; gi < TB * 32; gi += NT) {
            int v = gi >> 5, g = gi & 31;
            float4 x0 = *(const float4*)&rbuf[v][g * 8];
            float4 x1 = *(const float4*)&rbuf[v][g * 8 + 4];
            v8s o;
            o[0] = (short)f2bf(x0.x); o[1] = (short)f2bf(x0.y);
            o[2] = (short)f2bf(x0.z); o[3] = (short)f2bf(x0.w);
            o[4] = (short)f2bf(x1.x); o[5] = (short)f2bf(x1.y);
            o[6] = (short)f2bf(x1.z); o[7] = (short)f2bf(x1.w);
            *(v8s*)&rb16[v * Dd + ((g ^ (v & 7)) << 3)] = o;
        }
        __syncthreads();   // B1: rb16 + r2s + best64 visible to all waves

        const unsigned short* cbh_l = cbh + (size_t)l * Kk * Dd;
        const float* c2l = c2 + l * Kk;
        const float* cb  = cbks + (size_t)l * Kk * Dd;

        // ---- phase 2 (per wave, no block barrier): screen own 256 codes,
        //      then rescore own candidates ----
        const unsigned short* ap0 = &rb16[(size_t)lrow * Dd];
        const unsigned short* ap1 = &rb16[(size_t)(lrow + 16) * Dd];
        const int axor = lrow & 7;
        float mr[2][4];                // per-lane running row-min (registers)
        #pragma unroll
        for (int rt = 0; rt < 2; ++rt)
            #pragma unroll
            for (int reg = 0; reg < 4; ++reg) mr[rt][reg] = 1e30f;

        #pragma unroll
        for (int sc = 0; sc < 4; ++sc) {
            const int cbase = w * 256 + sc * 64;
            v4f acc[2][4];
            #pragma unroll
            for (int rt = 0; rt < 2; ++rt)
                #pragma unroll
                for (int ct = 0; ct < 4; ++ct) acc[rt][ct] = (v4f)(0.f);

            const unsigned short* bp[4];
            #pragma unroll
            for (int ct = 0; ct < 4; ++ct)
                bp[ct] = cbh_l + (size_t)(cbase + ct * 16 + lrow) * Dd + lk * 8;

            #pragma unroll
            for (int ks = 0; ks < 8; ++ks) {
                int aoff = (((ks * 4 + lk) ^ axor) << 3);
                v8s a0 = *(const v8s*)(ap0 + aoff);
                v8s a1 = *(const v8s*)(ap1 + aoff);
                #pragma unroll
                for (int ct = 0; ct < 4; ++ct) {
                    v8s b = *(const v8s*)(bp[ct] + ks * 32);
                    acc[0][ct] = __builtin_amdgcn_mfma_f32_16x16x32_bf16(a0, b, acc[0][ct], 0, 0, 0);
                    acc[1][ct] = __builtin_amdgcn_mfma_f32_16x16x32_bf16(a1, b, acc[1][ct], 0, 0, 0);
                }
            }

            float c2v[4];
            #pragma unroll
            for (int ct = 0; ct < 4; ++ct) c2v[ct] = c2l[cbase + ct * 16 + lrow];

            // candidate collection: C-layout col=lane&15, row=(lane>>4)*4+reg
            #pragma unroll
            for (int rt = 0; rt < 2; ++rt) {
                #pragma unroll
                for (int reg = 0; reg < 4; ++reg) {
                    int row = rt * 16 + lk * 4 + reg;
                    float t0 = c2v[0] - 2.f * acc[rt][0][reg];
                    float t1 = c2v[1] - 2.f * acc[rt][1][reg];
                    float t2 = c2v[2] - 2.f * acc[rt][2][reg];
                    float t3 = c2v[3] - 2.f * acc[rt][3][reg];
                    float pm = fminf(fminf(t0, t1), fminf(t2, t3));
                    pm = fminf(pm, __shfl_xor(pm, 1));
                    pm = fminf(pm, __shfl_xor(pm, 2));
                    pm = fminf(pm, __shfl_xor(pm, 4));
                    pm = fminf(pm, __shfl_xor(pm, 8));
                    float nm = fminf(mr[rt][reg], pm);
                    mr[rt][reg] = nm;
                    float th = nm + MARGIN;
                    if (t0 < th) { int p = atomicAdd(&cc[w], 1); if (p < CAPW) clist[w * CAPW + p] = (row << 10) | (cbase + 0 * 16 + lrow); }
                    if (t1 < th) { int p = atomicAdd(&cc[w], 1); if (p < CAPW) clist[w * CAPW + p] = (row << 10) | (cbase + 1 * 16 + lrow); }
                    if (t2 < th) { int p = atomicAdd(&cc[w], 1); if (p < CAPW) clist[w * CAPW + p] = (row << 10) | (cbase + 2 * 16 + lrow); }
                    if (t3 < th) { int p = atomicAdd(&cc[w], 1); if (p < CAPW) clist[w * CAPW + p] = (row << 10) | (cbase + 3 * 16 + lrow); }
                }
            }
        }

        // rescore own wave's candidates (exact np chain); fallback: own range
        {
            int cnt = cc[w];
            if (cnt <= CAPW) {
                for (int ci = lane; ci < cnt; ci += 64) {
                    int rc = clist[w * CAPW + ci];
                    int row = rc >> 10, code = rc & 1023;
                    const float* cp = cb + (size_t)code * Dd;
                    const float* rp = &rbuf[row][0];
                    float a = 0.f;
                    #pragma unroll 4
                    for (int d = 0; d < Dd; d += 4) {
                        float4 cv = *(const float4*)(cp + d);
                        a = __fmaf_rn(rp[d + 0], cv.x, a);
                        a = __fmaf_rn(rp[d + 1], cv.y, a);
                        a = __fmaf_rn(rp[d + 2], cv.z, a);
                        a = __fmaf_rn(rp[d + 3], cv.w, a);
                    }
                    float s = __fsub_rn(__fadd_rn(r2s[row], c2l[code]), 2.0f * a);
                    unsigned long long pk =
                        (((unsigned long long)__float_as_uint(s)) << 32) | (unsigned)code;
                    atomicMin(&best64[row], pk);
                }
            } else {
                for (int ci = lane; ci < TB * 256; ci += 64) {
                    int row = ci >> 8, code = w * 256 + (ci & 255);
                    const float* cp = cb + (size_t)code * Dd;
                    const float* rp = &rbuf[row][0];
                    float a = 0.f;
                    #pragma unroll 4
                    for (int d = 0; d < Dd; d += 4) {
                        float4 cv = *(const float4*)(cp + d);
                        a = __fmaf_rn(rp[d + 0], cv.x, a);
                        a = __fmaf_rn(rp[d + 1], cv.y, a);
                        a = __fmaf_rn(rp[d + 2], cv.z, a);
                        a = __fmaf_rn(rp[d + 3], cv.w, a);
                    }
                    float s = __fsub_rn(__fadd_rn(r2s[row], c2l[code]), 2.0f * a);
                    unsigned long long pk =
                        (((unsigned long long)__float_as_uint(s)) << 32) | (unsigned)code;
                    atomicMin(&best64[row], pk);
                }
            }
        }
        __syncthreads();   // B2: best64 final

        // ---- phase 3: gather chosen codes, update residual, emit outputs ----
        float ssq = 0.f;
        for (int v = w * 8; v < w * 8 + 8; ++v) {
            int idx = (int)(best64[v] & 0xffffffffu);
            if (lane == 0) out[O_IDX + (size_t)(b0 + v) * Ll + l] = (float)idx;
            size_t gb = (size_t)(b0 + v);
            const float4 q = *(const float4*)(cb + (size_t)idx * Dd + (lane << 2));
            float4 r = *(const float4*)&rbuf[v][lane << 2];
            float4 nr = make_float4(r.x - q.x, r.y - q.y, r.z - q.z, r.w - q.w);
            *(float4*)&rbuf[v][lane << 2] = nr;
            *(float4*)(out + O_QSTK + ((gb * Ll) + l) * Dd + (lane << 2)) = q;
            *(float4*)(out + O_RES + ((size_t)(l + 1) * Bsz + gb) * Dd + (lane << 2)) = nr;
            ssq += nr.x * nr.x + nr.y * nr.y + nr.z * nr.z + nr.w * nr.w;
        }
        #pragma unroll
        for (int m = 32; m; m >>= 1) ssq += __shfl_xor(ssq, m);
        if (lane == 0) wssq[w] = ssq;
        __syncthreads();   // B3: rbuf updated + wssq ready
        if (tid == 0)
            ws[wg * 4 + l] = wssq[0] + wssq[1] + wssq[2] + wssq[3];
    }

    // ---- streaming epilogue: quantized_sum / qspace from final residual ----
    for (int i = tid; i < TB * Dd / 4; i += NT) {
        int v  = i >> 6;
        int dp = (i & 63) << 2;
        size_t gb = (size_t)(b0 + v);
        float4 z = *(const float4*)(ze + gb * Dd + dp);
        float4 r = *(const float4*)&rbuf[v][dp];
        float4 qs = make_float4(z.x - r.x, z.y - r.y, z.z - r.z, z.w - r.w);
        *(float4*)(out + O_QSUM + gb * Dd + dp) = qs;
        float4 qq = make_float4(z.x + (qs.x - z.x), z.y + (qs.y - z.y),
                                z.z + (qs.z - z.z), z.w + (qs.w - z.w));
        *(float4*)(out + O_QSQ + gb * Dd + dp) = qq;
    }
}

// ---------------------------------------------------------------------------
// loss: deterministic reduction of per-WG partials -> 3 scalars
// ---------------------------------------------------------------------------
__global__ void loss_kernel(const float* __restrict__ ws, float* __restrict__ out) {
    __shared__ float red[Ll * 4];
    int tid = threadIdx.x;
    int lane = tid & 63, w = tid >> 6;
    for (int l = 0; l < Ll; ++l) {
        float s = 0.f;
        for (int i = tid; i < NWG; i += 256) s += ws[i * 4 + l];
        #pragma unroll
        for (int m = 32; m; m >>= 1) s += __shfl_xor(s, m);
        if (lane == 0) red[l * 4 + w] = s;
    }
    __syncthreads();
    if (tid == 0) {
        float tot = 0.f;
        for (int l = 0; l < Ll; ++l)
            tot += red[l * 4 + 0] + red[l * 4 + 1] + red[l * 4 + 2] + red[l * 4 + 3];
        float cm = tot / (float)((size_t)Ll * Bsz * Dd);
        out[O_LOSS + 0] = cm;                    // commitment_loss
        out[O_LOSS + 1] = cm;                    // codebook_loss
        out[O_LOSS + 2] = 0.25f * cm + cm;       // quantization_loss
    }
}

extern "C" void kernel_launch(void* const* d_in, const int* in_sizes, int n_in,
                              void* d_out, int out_size, void* d_ws, size_t ws_size,
                              hipStream_t stream) {
    (void)in_sizes; (void)n_in; (void)out_size; (void)ws_size;
    const float* ze   = (const float*)d_in[0];
    const float* cbks = (const float*)d_in[1];
    float* out = (float*)d_out;
    float* ws  = (float*)d_ws;

    hipLaunchKernelGGL(prep_kernel, dim3(16), dim3(256), 0, stream, cbks, ws);
    hipLaunchKernelGGL(cvt_kernel, dim3(Ll * Kk * Dd / 1024), dim3(256), 0, stream, cbks, ws);
    hipLaunchKernelGGL(rvq_kernel, dim3(NWG), dim3(NT), 0, stream, ze, cbks, out, ws);
    hipLaunchKernelGGL(loss_kernel, dim3(1), dim3(256), 0, stream, ws, out);
}